// Round 7
// baseline (420.884 us; speedup 1.0000x reference)
//
#include <hip/hip_runtime.h>
#include <hip/hip_bf16.h>
#include <stdint.h>

// Problem constants
// B=2, S=2048, HID=2048, NH=16, NKV=4, DH=128
// QKV fused GEMM: M=4096, K=2048, N=3072 (Q:0..2047, K:2048..2559, V:2560..3071)

typedef __attribute__((ext_vector_type(8))) short short8;
typedef __attribute__((ext_vector_type(4))) float floatx4;
typedef __hip_bfloat16 bf16_t;

#define MFMA16x16(a, b, c) __builtin_amdgcn_mfma_f32_16x16x32_bf16(a, b, c, 0, 0, 0)

__device__ __forceinline__ void async_copy16(const void* g, void* l) {
  __builtin_amdgcn_global_load_lds(
      (const __attribute__((address_space(1))) void*)g,
      (__attribute__((address_space(3))) void*)l, 16, 0, 0);
}

__device__ __forceinline__ unsigned short bf16bits(float x) {
  bf16_t h = __float2bfloat16(x);
  return *reinterpret_cast<unsigned short*>(&h);
}

// ---------------- f32 -> bf16 convert (vectorized) ----------------
__global__ __launch_bounds__(256) void convbf_kernel(const float* __restrict__ in,
                                                     bf16_t* __restrict__ out, int n4) {
  int i = blockIdx.x * 256 + threadIdx.x;
  if (i < n4) {
    const float4 v = reinterpret_cast<const float4*>(in)[i];
    ushort4 o;
    o.x = bf16bits(v.x); o.y = bf16bits(v.y); o.z = bf16bits(v.z); o.w = bf16bits(v.w);
    reinterpret_cast<ushort4*>(out)[i] = o;
  }
}

// ---------------- weight transpose f32[K][N] -> bf16[N][K], row offset ----------------
__global__ __launch_bounds__(256) void wtrans_kernel(const float* __restrict__ W,
                                                     bf16_t* __restrict__ Wt, int N, int roff) {
  __shared__ float t[32][33];
  int k0 = blockIdx.y * 32, n0 = blockIdx.x * 32;
#pragma unroll
  for (int j = 0; j < 4; ++j)
    t[threadIdx.y + j * 8][threadIdx.x] =
        W[(size_t)(k0 + threadIdx.y + j * 8) * N + n0 + threadIdx.x];
  __syncthreads();
#pragma unroll
  for (int j = 0; j < 4; ++j) {
    int n = n0 + threadIdx.y + j * 8, k = k0 + threadIdx.x;
    Wt[(size_t)(roff + n) * 2048 + k] = __float2bfloat16(t[threadIdx.x][threadIdx.y + j * 8]);
  }
}

// ---------------- GEMM: C[M][ldc](f32) = A[M][K](bf16) x Bt[N][K](bf16)^T ----------------
__global__ __launch_bounds__(256) void gemm_bt_kernel(const bf16_t* __restrict__ A,
                                                      const bf16_t* __restrict__ Bt,
                                                      float* __restrict__ C,
                                                      int K, int ldc) {
  __shared__ __align__(16) char smem[32768];
  const int tid = threadIdx.x;
  const int wave = tid >> 6, lane = tid & 63;
  const int wr = wave >> 1, wc = wave & 1;
  const int l16 = lane & 15, lhi = lane >> 4;
  const int bm = blockIdx.y * 128, bn = blockIdx.x * 128;

  floatx4 acc[4][4] = {};

  for (int k0 = 0; k0 < K; k0 += 64) {
    __syncthreads();
#pragma unroll
    for (int i = 0; i < 4; ++i) {
      int chunk = i * 4 + wave;
      unsigned p = (unsigned)chunk * 1024u + (unsigned)lane * 16u;
      unsigned row = p >> 7;
      unsigned colg = (p & 127u) ^ ((row & 7u) << 4);
      const char* gA = (const char*)(A + (size_t)(bm + row) * K + k0) + colg;
      async_copy16(gA, smem + (size_t)chunk * 1024);
      const char* gB = (const char*)(Bt + (size_t)(bn + row) * K + k0) + colg;
      async_copy16(gB, smem + 16384 + (size_t)chunk * 1024);
    }
    __syncthreads();
#pragma unroll
    for (int kk = 0; kk < 2; ++kk) {
      short8 fa[4], fb[4];
#pragma unroll
      for (int mi = 0; mi < 4; ++mi) {
        unsigned row = wr * 64 + mi * 16 + l16;
        unsigned off = row * 128u + kk * 64u + lhi * 16u;
        off ^= (row & 7u) << 4;
        fa[mi] = *(const short8*)(smem + off);
      }
#pragma unroll
      for (int ni = 0; ni < 4; ++ni) {
        unsigned row = wc * 64 + ni * 16 + l16;
        unsigned off = row * 128u + kk * 64u + lhi * 16u;
        off ^= (row & 7u) << 4;
        fb[ni] = *(const short8*)(smem + 16384 + off);
      }
#pragma unroll
      for (int mi = 0; mi < 4; ++mi)
#pragma unroll
        for (int ni = 0; ni < 4; ++ni)
          acc[mi][ni] = MFMA16x16(fa[mi], fb[ni], acc[mi][ni]);
    }
  }
#pragma unroll
  for (int mi = 0; mi < 4; ++mi)
#pragma unroll
    for (int ni = 0; ni < 4; ++ni)
#pragma unroll
      for (int r = 0; r < 4; ++r) {
        int row = bm + wr * 64 + mi * 16 + lhi * 4 + r;
        int col = bn + wc * 64 + ni * 16 + l16;
        C[(size_t)row * ldc + col] = acc[mi][ni][r];
      }
}

// ---------------- RMSNorm + RoPE + relayout for Q and K ----------------
// Q additionally pre-scaled by 1/sqrt(DH) so flash drops the scale multiply.
__global__ __launch_bounds__(256) void qknorm_rope_kernel(
    const float* __restrict__ Cqkv, const float* __restrict__ cosT,
    const float* __restrict__ sinT, const float* __restrict__ qw,
    const float* __restrict__ kw, bf16_t* __restrict__ Qa, bf16_t* __restrict__ Ka) {
  int wave = threadIdx.x >> 6, lane = threadIdx.x & 63;
  int task = blockIdx.x * 4 + wave;
  int unit = task % 20;
  int row = task / 20;
  int b = row >> 11, s = row & 2047;
  const float* src;
  const float* w;
  bf16_t* dst;
  float sc;
  if (unit < 16) {
    src = Cqkv + (size_t)row * 3072 + unit * 128;
    w = qw;
    dst = Qa + ((size_t)(b * 16 + unit) * 2048 + s) * 128;
    sc = 0.088388347648318447f;  // 1/sqrt(128)
  } else {
    int kh = unit - 16;
    src = Cqkv + (size_t)row * 3072 + 2048 + kh * 128;
    w = kw;
    dst = Ka + ((size_t)(b * 4 + kh) * 2048 + s) * 128;
    sc = 1.0f;
  }
  float x1 = src[lane], x2 = src[lane + 64];
  float ss = x1 * x1 + x2 * x2;
#pragma unroll
  for (int off = 1; off < 64; off <<= 1) ss += __shfl_xor(ss, off, 64);
  float inv = rsqrtf(ss * (1.f / 128.f) + 1e-6f);
  x1 = x1 * inv * w[lane];
  x2 = x2 * inv * w[lane + 64];
  float c1 = cosT[(size_t)s * 128 + lane], c2 = cosT[(size_t)s * 128 + lane + 64];
  float s1 = sinT[(size_t)s * 128 + lane], s2 = sinT[(size_t)s * 128 + lane + 64];
  dst[lane] = __float2bfloat16((x1 * c1 - x2 * s1) * sc);
  dst[lane + 64] = __float2bfloat16((x2 * c2 + x1 * s2) * sc);
}

// ---------------- V transpose: Cqkv f32 -> Vt[b][kh][d][s] bf16 ----------------
__global__ __launch_bounds__(256) void vtrans_kernel(const float* __restrict__ Cqkv,
                                                     bf16_t* __restrict__ Vt) {
  __shared__ float t[32][33];
  int bk = blockIdx.z;
  int b = bk >> 2, kh = bk & 3;
  int s0 = blockIdx.x * 32, d0 = blockIdx.y * 32;
  const float* src = Cqkv + (size_t)(b * 2048) * 3072 + 2560 + kh * 128;
#pragma unroll
  for (int j = 0; j < 4; ++j)
    t[threadIdx.y + j * 8][threadIdx.x] =
        src[(size_t)(s0 + threadIdx.y + j * 8) * 3072 + d0 + threadIdx.x];
  __syncthreads();
  bf16_t* dst = Vt + (size_t)(b * 4 + kh) * 128 * 2048;
#pragma unroll
  for (int j = 0; j < 4; ++j) {
    int d = d0 + threadIdx.y + j * 8, s = s0 + threadIdx.x;
    dst[(size_t)d * 2048 + s] = __float2bfloat16(t[threadIdx.x][threadIdx.y + j * 8]);
  }
}

// ---------------- Flash attention v3 (causal, GQA) ----------------
// 4 waves x 32 Q-rows = 128 rows/block; KV chunk = 64 keys.
// 48KB LDS (K single 16K + V 16K + P 4x4K) -> 3 blocks/CU (12 waves).
// Pipeline: [K_c,V_c staged] QK+softmax -> bar1 (drains V_c) -> issue K_{c+1}
//           -> PV -> bar2 (drains K_{c+1}) -> issue V_{c+1}.
// l computed via ones-column MFMA (P x 1) instead of shfl reduce; defer-max THR=8;
// mask-skip on interior chunks; Q pre-scaled; setprio around MFMA clusters.
__global__ __launch_bounds__(256, 3) void flash_kernel(const bf16_t* __restrict__ Qa,
                                                       const bf16_t* __restrict__ Ka,
                                                       const bf16_t* __restrict__ Vt,
                                                       bf16_t* __restrict__ attnO) {
  __shared__ __align__(16) char smem[49152];
  const int tid = threadIdx.x;
  const int wave = tid >> 6, lane = tid & 63;
  const int l16 = lane & 15, lhi = lane >> 4;
  const int bid = blockIdx.x;          // 512 blocks
  const int bh = bid & 31;             // b*16 + h
  const int ib = bid >> 5;             // 0..15
  const int qb = (ib < 8) ? (15 - ib) : (ib - 8);  // heavy 15..8, then light 0..7
  const int h = bh & 15, b = bh >> 4;
  const int kh = h >> 2;
  const int q0b = qb << 7;
  const int q0w = q0b + wave * 32;

  const bf16_t* Qb = Qa + ((size_t)bh * 2048 + q0w) * 128;
  const bf16_t* Kb = Ka + (size_t)(b * 4 + kh) * 2048 * 128;
  const bf16_t* Vb = Vt + (size_t)(b * 4 + kh) * 128 * 2048;

  char* Kl = smem;                       // [64][128] bf16, 256B/row, XOR swz
  char* Vl = smem + 16384;               // [128][64] bf16, 128B/row, XOR swz
  char* Pl = smem + 32768 + wave * 4096; // per-wave [32][64] bf16, XOR swz

  // Q fragments in registers: rows q0w + rt*16 + l16, dims kk*32 + lhi*8
  short8 qf[2][4];
#pragma unroll
  for (int rt = 0; rt < 2; ++rt)
#pragma unroll
    for (int kk = 0; kk < 4; ++kk)
      qf[rt][kk] = *(const short8*)(Qb + (size_t)(rt * 16 + l16) * 128 + kk * 32 + lhi * 8);

  short8 onesf;
#pragma unroll
  for (int j = 0; j < 8; ++j) onesf[j] = (short)0x3F80;  // bf16 1.0

  floatx4 o[2][8] = {};
  floatx4 lsum[2] = {};
  float m[2][4];
#pragma unroll
  for (int rt = 0; rt < 2; ++rt)
#pragma unroll
    for (int r = 0; r < 4; ++r) m[rt][r] = -1e30f;

  const float THR = 8.0f;
  const int nch = 2 * qb + 2;
  const unsigned pswz_rd = (unsigned)(l16 & 7) << 4;

  // prologue: stage K_0 and V_0
#pragma unroll
  for (int it = 0; it < 4; ++it) {
    unsigned base = (unsigned)(it * 4 + wave) * 1024u;
    unsigned p = base + (unsigned)lane * 16u;
    unsigned row = p >> 8, col = p & 255u;
    unsigned gcol = col ^ ((row & 7u) << 4);
    async_copy16((const char*)(Kb + (size_t)row * 128) + gcol, Kl + base);
  }
#pragma unroll
  for (int it = 0; it < 4; ++it) {
    unsigned base = (unsigned)(it * 4 + wave) * 1024u;
    unsigned p = base + (unsigned)lane * 16u;
    unsigned row = p >> 7, col = p & 127u;
    unsigned gcol = col ^ ((row & 7u) << 4);
    async_copy16((const char*)(Vb + (size_t)row * 2048) + gcol, Vl + base);
  }
  __syncthreads();

  for (int c = 0; c < nch; ++c) {
    const int kc0 = c << 6;
    const bool active = (kc0 <= q0w + 31);

    if (active) {
      // QK^T
      floatx4 s[2][4] = {};
      __builtin_amdgcn_s_setprio(1);
#pragma unroll
      for (int kk = 0; kk < 4; ++kk) {
#pragma unroll
        for (int kt = 0; kt < 4; ++kt) {
          unsigned off = (unsigned)(kt * 16 + l16) * 256u +
                         (((unsigned)(kk * 64 + lhi * 16)) ^ pswz_rd);
          short8 kf = *(const short8*)(Kl + off);
          s[0][kt] = MFMA16x16(qf[0][kk], kf, s[0][kt]);
          s[1][kt] = MFMA16x16(qf[1][kk], kf, s[1][kt]);
        }
      }
      __builtin_amdgcn_s_setprio(0);

      const bool needMask = (kc0 + 64 > q0w);
      // online softmax (defer-max)
#pragma unroll
      for (int rt = 0; rt < 2; ++rt) {
        float mx[4];
#pragma unroll
        for (int r = 0; r < 4; ++r) {
          if (needMask) {
            int qrow = q0w + rt * 16 + lhi * 4 + r;
#pragma unroll
            for (int kt = 0; kt < 4; ++kt)
              s[rt][kt][r] += ((kc0 + kt * 16 + l16) > qrow ? -1e9f : 0.f);
          }
          float t = fmaxf(fmaxf(s[rt][0][r], s[rt][1][r]), fmaxf(s[rt][2][r], s[rt][3][r]));
#pragma unroll
          for (int off = 1; off < 16; off <<= 1) t = fmaxf(t, __shfl_xor(t, off, 64));
          mx[r] = t;
        }
        bool grow = (mx[0] > m[rt][0] + THR) | (mx[1] > m[rt][1] + THR) |
                    (mx[2] > m[rt][2] + THR) | (mx[3] > m[rt][3] + THR);
        if (__any(grow)) {
#pragma unroll
          for (int r = 0; r < 4; ++r) {
            float mn = fmaxf(m[rt][r], mx[r]);
            float corr = __expf(m[rt][r] - mn);
            m[rt][r] = mn;
            lsum[rt][r] *= corr;
#pragma unroll
            for (int f = 0; f < 8; ++f) o[rt][f][r] *= corr;
          }
        }
#pragma unroll
        for (int r = 0; r < 4; ++r) {
          int prow = rt * 16 + lhi * 4 + r;
          unsigned ps_w = (unsigned)(prow & 7) << 4;
#pragma unroll
          for (int kt = 0; kt < 4; ++kt) {
            float p = __expf(s[rt][kt][r] - m[rt][r]);
            unsigned off = (unsigned)prow * 128u + ((((unsigned)(kt * 16 + l16)) * 2u) ^ ps_w);
            *(unsigned short*)(Pl + off) = bf16bits(p);
          }
        }
      }
    }

    __syncthreads();  // all waves: QK done (K free), V_c drained, P visible to self

    // issue K_{c+1} staging (lands during PV)
    if (c + 1 < nch) {
#pragma unroll
      for (int it = 0; it < 4; ++it) {
        unsigned base = (unsigned)(it * 4 + wave) * 1024u;
        unsigned p = base + (unsigned)lane * 16u;
        unsigned row = p >> 8, col = p & 255u;
        unsigned gcol = col ^ ((row & 7u) << 4);
        async_copy16((const char*)(Kb + (size_t)(kc0 + 64 + row) * 128) + gcol, Kl + base);
      }
    }

    if (active) {
      // PV + ones-column row-sum
      __builtin_amdgcn_s_setprio(1);
#pragma unroll
      for (int ks = 0; ks < 2; ++ks) {
        short8 vf[8];
#pragma unroll
        for (int f = 0; f < 8; ++f) {
          unsigned off = (unsigned)(f * 16 + l16) * 128u +
                         (((unsigned)(ks * 64 + lhi * 16)) ^ pswz_rd);
          vf[f] = *(const short8*)(Vl + off);
        }
#pragma unroll
        for (int rt = 0; rt < 2; ++rt) {
          unsigned off = (unsigned)(rt * 16 + l16) * 128u +
                         (((unsigned)(ks * 64 + lhi * 16)) ^ pswz_rd);
          short8 pf = *(const short8*)(Pl + off);
#pragma unroll
          for (int f = 0; f < 8; ++f) o[rt][f] = MFMA16x16(pf, vf[f], o[rt][f]);
          lsum[rt] = MFMA16x16(pf, onesf, lsum[rt]);
        }
      }
      __builtin_amdgcn_s_setprio(0);
    }

    __syncthreads();  // all waves done with Vl/Pl; K_{c+1} drained

    // issue V_{c+1} staging (lands during next QK+softmax)
    if (c + 1 < nch) {
#pragma unroll
      for (int it = 0; it < 4; ++it) {
        unsigned base = (unsigned)(it * 4 + wave) * 1024u;
        unsigned p = base + (unsigned)lane * 16u;
        unsigned row = p >> 7, col = p & 127u;
        unsigned gcol = col ^ ((row & 7u) << 4);
        async_copy16((const char*)(Vb + (size_t)row * 2048 + kc0 + 64) + gcol, Vl + base);
      }
    }
  }

  // epilogue
#pragma unroll
  for (int rt = 0; rt < 2; ++rt)
#pragma unroll
    for (int r = 0; r < 4; ++r) {
      float inv = 1.f / lsum[rt][r];
      int row = q0w + rt * 16 + lhi * 4 + r;
      size_t base = ((size_t)(b * 2048) + row) * 2048 + h * 128;
#pragma unroll
      for (int f = 0; f < 8; ++f)
        attnO[base + f * 16 + l16] = __float2bfloat16(o[rt][f][r] * inv);
    }
}

// ---------------- launch ----------------
extern "C" void kernel_launch(void* const* d_in, const int* in_sizes, int n_in,
                              void* d_out, int out_size, void* d_ws, size_t ws_size,
                              hipStream_t stream) {
  const float* hs = (const float*)d_in[0];
  const float* cosT = (const float*)d_in[2];
  const float* sinT = (const float*)d_in[3];
  const float* Wq = (const float*)d_in[4];
  const float* Wk = (const float*)d_in[5];
  const float* Wv = (const float*)d_in[6];
  const float* Wo = (const float*)d_in[7];
  const float* qw = (const float*)d_in[8];
  const float* kw = (const float*)d_in[9];
  float* out = (float*)d_out;

  char* ws = (char*)d_ws;
  size_t off = 0;
  auto alloc = [&](size_t bytes) {
    char* p = ws + off;
    off += (bytes + 255) & ~(size_t)255;
    return p;
  };
  bf16_t* hsb  = (bf16_t*)alloc((size_t)4096 * 2048 * 2);
  bf16_t* wqkv = (bf16_t*)alloc((size_t)3072 * 2048 * 2);
  bf16_t* wot  = (bf16_t*)alloc((size_t)2048 * 2048 * 2);
  float*  cqkv = (float*)alloc((size_t)4096 * 3072 * 4);
  bf16_t* qa   = (bf16_t*)alloc((size_t)2 * 16 * 2048 * 128 * 2);
  bf16_t* ka   = (bf16_t*)alloc((size_t)2 * 4 * 2048 * 128 * 2);
  bf16_t* vt   = (bf16_t*)alloc((size_t)2 * 4 * 2048 * 128 * 2);
  bf16_t* attn = (bf16_t*)cqkv;

  convbf_kernel<<<8192, 256, 0, stream>>>(hs, hsb, 2097152);
  dim3 tb(32, 8);
  wtrans_kernel<<<dim3(64, 64), tb, 0, stream>>>(Wq, wqkv, 2048, 0);
  wtrans_kernel<<<dim3(16, 64), tb, 0, stream>>>(Wk, wqkv, 512, 2048);
  wtrans_kernel<<<dim3(16, 64), tb, 0, stream>>>(Wv, wqkv, 512, 2560);
  wtrans_kernel<<<dim3(64, 64), tb, 0, stream>>>(Wo, wot, 2048, 0);
  gemm_bt_kernel<<<dim3(24, 32), 256, 0, stream>>>(hsb, wqkv, cqkv, 2048, 3072);
  qknorm_rope_kernel<<<20480, 256, 0, stream>>>(cqkv, cosT, sinT, qw, kw, qa, ka);
  vtrans_kernel<<<dim3(64, 4, 8), tb, 0, stream>>>(cqkv, vt);
  flash_kernel<<<512, 256, 0, stream>>>(qa, ka, vt, attn);
  gemm_bt_kernel<<<dim3(16, 32), 256, 0, stream>>>(attn, wot, out, 2048, 2048);
}

// Round 8
// 262.689 us; speedup vs baseline: 1.6022x; 1.6022x over previous
//
#include <hip/hip_runtime.h>
#include <hip/hip_bf16.h>
#include <stdint.h>

// Problem constants
// B=2, S=2048, HID=2048, NH=16, NKV=4, DH=128
// QKV fused GEMM: M=4096, K=2048, N=3072 (Q:0..2047, K:2048..2559, V:2560..3071)

typedef __attribute__((ext_vector_type(8))) short short8;
typedef __attribute__((ext_vector_type(4))) float floatx4;
typedef __hip_bfloat16 bf16_t;

#define MFMA16x16(a, b, c) __builtin_amdgcn_mfma_f32_16x16x32_bf16(a, b, c, 0, 0, 0)

__device__ __forceinline__ void async_copy16(const void* g, void* l) {
  __builtin_amdgcn_global_load_lds(
      (const __attribute__((address_space(1))) void*)g,
      (__attribute__((address_space(3))) void*)l, 16, 0, 0);
}

__device__ __forceinline__ unsigned short bf16bits(float x) {
  bf16_t h = __float2bfloat16(x);
  return *reinterpret_cast<unsigned short*>(&h);
}

// ---------------- f32 -> bf16 convert (vectorized) ----------------
__global__ __launch_bounds__(256) void convbf_kernel(const float* __restrict__ in,
                                                     bf16_t* __restrict__ out, int n4) {
  int i = blockIdx.x * 256 + threadIdx.x;
  if (i < n4) {
    const float4 v = reinterpret_cast<const float4*>(in)[i];
    ushort4 o;
    o.x = bf16bits(v.x); o.y = bf16bits(v.y); o.z = bf16bits(v.z); o.w = bf16bits(v.w);
    reinterpret_cast<ushort4*>(out)[i] = o;
  }
}

// ---------------- weight transpose f32[K][N] -> bf16[N][K], row offset ----------------
__global__ __launch_bounds__(256) void wtrans_kernel(const float* __restrict__ W,
                                                     bf16_t* __restrict__ Wt, int N, int roff) {
  __shared__ float t[32][33];
  int k0 = blockIdx.y * 32, n0 = blockIdx.x * 32;
#pragma unroll
  for (int j = 0; j < 4; ++j)
    t[threadIdx.y + j * 8][threadIdx.x] =
        W[(size_t)(k0 + threadIdx.y + j * 8) * N + n0 + threadIdx.x];
  __syncthreads();
#pragma unroll
  for (int j = 0; j < 4; ++j) {
    int n = n0 + threadIdx.y + j * 8, k = k0 + threadIdx.x;
    Wt[(size_t)(roff + n) * 2048 + k] = __float2bfloat16(t[threadIdx.x][threadIdx.y + j * 8]);
  }
}

// ---------------- GEMM: C[M][ldc](f32) = A[M][K](bf16) x Bt[N][K](bf16)^T ----------------
__global__ __launch_bounds__(256) void gemm_bt_kernel(const bf16_t* __restrict__ A,
                                                      const bf16_t* __restrict__ Bt,
                                                      float* __restrict__ C,
                                                      int K, int ldc) {
  __shared__ __align__(16) char smem[32768];
  const int tid = threadIdx.x;
  const int wave = tid >> 6, lane = tid & 63;
  const int wr = wave >> 1, wc = wave & 1;
  const int l16 = lane & 15, lhi = lane >> 4;
  const int bm = blockIdx.y * 128, bn = blockIdx.x * 128;

  floatx4 acc[4][4] = {};

  for (int k0 = 0; k0 < K; k0 += 64) {
    __syncthreads();
#pragma unroll
    for (int i = 0; i < 4; ++i) {
      int chunk = i * 4 + wave;
      unsigned p = (unsigned)chunk * 1024u + (unsigned)lane * 16u;
      unsigned row = p >> 7;
      unsigned colg = (p & 127u) ^ ((row & 7u) << 4);
      const char* gA = (const char*)(A + (size_t)(bm + row) * K + k0) + colg;
      async_copy16(gA, smem + (size_t)chunk * 1024);
      const char* gB = (const char*)(Bt + (size_t)(bn + row) * K + k0) + colg;
      async_copy16(gB, smem + 16384 + (size_t)chunk * 1024);
    }
    __syncthreads();
#pragma unroll
    for (int kk = 0; kk < 2; ++kk) {
      short8 fa[4], fb[4];
#pragma unroll
      for (int mi = 0; mi < 4; ++mi) {
        unsigned row = wr * 64 + mi * 16 + l16;
        unsigned off = row * 128u + kk * 64u + lhi * 16u;
        off ^= (row & 7u) << 4;
        fa[mi] = *(const short8*)(smem + off);
      }
#pragma unroll
      for (int ni = 0; ni < 4; ++ni) {
        unsigned row = wc * 64 + ni * 16 + l16;
        unsigned off = row * 128u + kk * 64u + lhi * 16u;
        off ^= (row & 7u) << 4;
        fb[ni] = *(const short8*)(smem + 16384 + off);
      }
#pragma unroll
      for (int mi = 0; mi < 4; ++mi)
#pragma unroll
        for (int ni = 0; ni < 4; ++ni)
          acc[mi][ni] = MFMA16x16(fa[mi], fb[ni], acc[mi][ni]);
    }
  }
#pragma unroll
  for (int mi = 0; mi < 4; ++mi)
#pragma unroll
    for (int ni = 0; ni < 4; ++ni)
#pragma unroll
      for (int r = 0; r < 4; ++r) {
        int row = bm + wr * 64 + mi * 16 + lhi * 4 + r;
        int col = bn + wc * 64 + ni * 16 + l16;
        C[(size_t)row * ldc + col] = acc[mi][ni][r];
      }
}

// ---------------- RMSNorm + RoPE + relayout for Q and K ----------------
// Q additionally pre-scaled by 1/sqrt(DH) so flash drops the scale multiply.
__global__ __launch_bounds__(256) void qknorm_rope_kernel(
    const float* __restrict__ Cqkv, const float* __restrict__ cosT,
    const float* __restrict__ sinT, const float* __restrict__ qw,
    const float* __restrict__ kw, bf16_t* __restrict__ Qa, bf16_t* __restrict__ Ka) {
  int wave = threadIdx.x >> 6, lane = threadIdx.x & 63;
  int task = blockIdx.x * 4 + wave;
  int unit = task % 20;
  int row = task / 20;
  int b = row >> 11, s = row & 2047;
  const float* src;
  const float* w;
  bf16_t* dst;
  float sc;
  if (unit < 16) {
    src = Cqkv + (size_t)row * 3072 + unit * 128;
    w = qw;
    dst = Qa + ((size_t)(b * 16 + unit) * 2048 + s) * 128;
    sc = 0.088388347648318447f;  // 1/sqrt(128)
  } else {
    int kh = unit - 16;
    src = Cqkv + (size_t)row * 3072 + 2048 + kh * 128;
    w = kw;
    dst = Ka + ((size_t)(b * 4 + kh) * 2048 + s) * 128;
    sc = 1.0f;
  }
  float x1 = src[lane], x2 = src[lane + 64];
  float ss = x1 * x1 + x2 * x2;
#pragma unroll
  for (int off = 1; off < 64; off <<= 1) ss += __shfl_xor(ss, off, 64);
  float inv = rsqrtf(ss * (1.f / 128.f) + 1e-6f);
  x1 = x1 * inv * w[lane];
  x2 = x2 * inv * w[lane + 64];
  float c1 = cosT[(size_t)s * 128 + lane], c2 = cosT[(size_t)s * 128 + lane + 64];
  float s1 = sinT[(size_t)s * 128 + lane], s2 = sinT[(size_t)s * 128 + lane + 64];
  dst[lane] = __float2bfloat16((x1 * c1 - x2 * s1) * sc);
  dst[lane + 64] = __float2bfloat16((x2 * c2 + x1 * s2) * sc);
}

// ---------------- V transpose: Cqkv f32 -> Vt[b][kh][d][s] bf16 ----------------
__global__ __launch_bounds__(256) void vtrans_kernel(const float* __restrict__ Cqkv,
                                                     bf16_t* __restrict__ Vt) {
  __shared__ float t[32][33];
  int bk = blockIdx.z;
  int b = bk >> 2, kh = bk & 3;
  int s0 = blockIdx.x * 32, d0 = blockIdx.y * 32;
  const float* src = Cqkv + (size_t)(b * 2048) * 3072 + 2560 + kh * 128;
#pragma unroll
  for (int j = 0; j < 4; ++j)
    t[threadIdx.y + j * 8][threadIdx.x] =
        src[(size_t)(s0 + threadIdx.y + j * 8) * 3072 + d0 + threadIdx.x];
  __syncthreads();
  bf16_t* dst = Vt + (size_t)(b * 4 + kh) * 128 * 2048;
#pragma unroll
  for (int j = 0; j < 4; ++j) {
    int d = d0 + threadIdx.y + j * 8, s = s0 + threadIdx.x;
    dst[(size_t)d * 2048 + s] = __float2bfloat16(t[threadIdx.x][threadIdx.y + j * 8]);
  }
}

// ---------------- Flash attention v4 (causal, GQA) ----------------
// v3 structure with launch_bounds(256,2): VGPR cap 256 (no accumulator spill;
// v3's (256,3) capped at 84 VGPRs and spilled -> 160MB scratch HBM traffic).
// 4 waves x 32 Q-rows = 128 rows/block; KV chunk = 64 keys; 48KB LDS.
// Pipeline: [K_c,V_c staged] QK+softmax -> bar1 (drains V_c) -> issue K_{c+1}
//           -> PV -> bar2 (drains K_{c+1}) -> issue V_{c+1}.
// l via ones-column MFMA; defer-max THR=8; mask only on diagonal chunks;
// Q pre-scaled; active-guard; heavy/light block pairing; setprio on MFMA.
__global__ __launch_bounds__(256, 2) void flash_kernel(const bf16_t* __restrict__ Qa,
                                                       const bf16_t* __restrict__ Ka,
                                                       const bf16_t* __restrict__ Vt,
                                                       bf16_t* __restrict__ attnO) {
  __shared__ __align__(16) char smem[49152];
  const int tid = threadIdx.x;
  const int wave = tid >> 6, lane = tid & 63;
  const int l16 = lane & 15, lhi = lane >> 4;
  const int bid = blockIdx.x;          // 512 blocks
  const int bh = bid & 31;             // b*16 + h
  const int ib = bid >> 5;             // 0..15
  const int qb = (ib < 8) ? (15 - ib) : (ib - 8);  // heavy 15..8, then light 0..7
  const int h = bh & 15, b = bh >> 4;
  const int kh = h >> 2;
  const int q0b = qb << 7;
  const int q0w = q0b + wave * 32;

  const bf16_t* Qb = Qa + ((size_t)bh * 2048 + q0w) * 128;
  const bf16_t* Kb = Ka + (size_t)(b * 4 + kh) * 2048 * 128;
  const bf16_t* Vb = Vt + (size_t)(b * 4 + kh) * 128 * 2048;

  char* Kl = smem;                       // [64][128] bf16, 256B/row, XOR swz
  char* Vl = smem + 16384;               // [128][64] bf16, 128B/row, XOR swz
  char* Pl = smem + 32768 + wave * 4096; // per-wave [32][64] bf16, XOR swz

  // Q fragments in registers: rows q0w + rt*16 + l16, dims kk*32 + lhi*8
  short8 qf[2][4];
#pragma unroll
  for (int rt = 0; rt < 2; ++rt)
#pragma unroll
    for (int kk = 0; kk < 4; ++kk)
      qf[rt][kk] = *(const short8*)(Qb + (size_t)(rt * 16 + l16) * 128 + kk * 32 + lhi * 8);

  short8 onesf;
#pragma unroll
  for (int j = 0; j < 8; ++j) onesf[j] = (short)0x3F80;  // bf16 1.0

  floatx4 o[2][8] = {};
  floatx4 lsum[2] = {};
  float m[2][4];
#pragma unroll
  for (int rt = 0; rt < 2; ++rt)
#pragma unroll
    for (int r = 0; r < 4; ++r) m[rt][r] = -1e30f;

  const float THR = 8.0f;
  const int nch = 2 * qb + 2;
  const unsigned pswz_rd = (unsigned)(l16 & 7) << 4;

  // prologue: stage K_0 and V_0
#pragma unroll
  for (int it = 0; it < 4; ++it) {
    unsigned base = (unsigned)(it * 4 + wave) * 1024u;
    unsigned p = base + (unsigned)lane * 16u;
    unsigned row = p >> 8, col = p & 255u;
    unsigned gcol = col ^ ((row & 7u) << 4);
    async_copy16((const char*)(Kb + (size_t)row * 128) + gcol, Kl + base);
  }
#pragma unroll
  for (int it = 0; it < 4; ++it) {
    unsigned base = (unsigned)(it * 4 + wave) * 1024u;
    unsigned p = base + (unsigned)lane * 16u;
    unsigned row = p >> 7, col = p & 127u;
    unsigned gcol = col ^ ((row & 7u) << 4);
    async_copy16((const char*)(Vb + (size_t)row * 2048) + gcol, Vl + base);
  }
  __syncthreads();

  for (int c = 0; c < nch; ++c) {
    const int kc0 = c << 6;
    const bool active = (kc0 <= q0w + 31);

    if (active) {
      // QK^T
      floatx4 s[2][4] = {};
      __builtin_amdgcn_s_setprio(1);
#pragma unroll
      for (int kk = 0; kk < 4; ++kk) {
#pragma unroll
        for (int kt = 0; kt < 4; ++kt) {
          unsigned off = (unsigned)(kt * 16 + l16) * 256u +
                         (((unsigned)(kk * 64 + lhi * 16)) ^ pswz_rd);
          short8 kf = *(const short8*)(Kl + off);
          s[0][kt] = MFMA16x16(qf[0][kk], kf, s[0][kt]);
          s[1][kt] = MFMA16x16(qf[1][kk], kf, s[1][kt]);
        }
      }
      __builtin_amdgcn_s_setprio(0);

      const bool needMask = (kc0 + 64 > q0w);
      // online softmax (defer-max)
#pragma unroll
      for (int rt = 0; rt < 2; ++rt) {
        float mx[4];
#pragma unroll
        for (int r = 0; r < 4; ++r) {
          if (needMask) {
            int qrow = q0w + rt * 16 + lhi * 4 + r;
#pragma unroll
            for (int kt = 0; kt < 4; ++kt)
              s[rt][kt][r] += ((kc0 + kt * 16 + l16) > qrow ? -1e9f : 0.f);
          }
          float t = fmaxf(fmaxf(s[rt][0][r], s[rt][1][r]), fmaxf(s[rt][2][r], s[rt][3][r]));
#pragma unroll
          for (int off = 1; off < 16; off <<= 1) t = fmaxf(t, __shfl_xor(t, off, 64));
          mx[r] = t;
        }
        bool grow = (mx[0] > m[rt][0] + THR) | (mx[1] > m[rt][1] + THR) |
                    (mx[2] > m[rt][2] + THR) | (mx[3] > m[rt][3] + THR);
        if (__any(grow)) {
#pragma unroll
          for (int r = 0; r < 4; ++r) {
            float mn = fmaxf(m[rt][r], mx[r]);
            float corr = __expf(m[rt][r] - mn);
            m[rt][r] = mn;
            lsum[rt][r] *= corr;
#pragma unroll
            for (int f = 0; f < 8; ++f) o[rt][f][r] *= corr;
          }
        }
#pragma unroll
        for (int r = 0; r < 4; ++r) {
          int prow = rt * 16 + lhi * 4 + r;
          unsigned ps_w = (unsigned)(prow & 7) << 4;
#pragma unroll
          for (int kt = 0; kt < 4; ++kt) {
            float p = __expf(s[rt][kt][r] - m[rt][r]);
            unsigned off = (unsigned)prow * 128u + ((((unsigned)(kt * 16 + l16)) * 2u) ^ ps_w);
            *(unsigned short*)(Pl + off) = bf16bits(p);
          }
        }
      }
    }

    __syncthreads();  // all waves: QK done (K free), V_c drained, P visible to self

    // issue K_{c+1} staging (lands during PV)
    if (c + 1 < nch) {
#pragma unroll
      for (int it = 0; it < 4; ++it) {
        unsigned base = (unsigned)(it * 4 + wave) * 1024u;
        unsigned p = base + (unsigned)lane * 16u;
        unsigned row = p >> 8, col = p & 255u;
        unsigned gcol = col ^ ((row & 7u) << 4);
        async_copy16((const char*)(Kb + (size_t)(kc0 + 64 + row) * 128) + gcol, Kl + base);
      }
    }

    if (active) {
      // PV + ones-column row-sum
      __builtin_amdgcn_s_setprio(1);
#pragma unroll
      for (int ks = 0; ks < 2; ++ks) {
        short8 vf[8];
#pragma unroll
        for (int f = 0; f < 8; ++f) {
          unsigned off = (unsigned)(f * 16 + l16) * 128u +
                         (((unsigned)(ks * 64 + lhi * 16)) ^ pswz_rd);
          vf[f] = *(const short8*)(Vl + off);
        }
#pragma unroll
        for (int rt = 0; rt < 2; ++rt) {
          unsigned off = (unsigned)(rt * 16 + l16) * 128u +
                         (((unsigned)(ks * 64 + lhi * 16)) ^ pswz_rd);
          short8 pf = *(const short8*)(Pl + off);
#pragma unroll
          for (int f = 0; f < 8; ++f) o[rt][f] = MFMA16x16(pf, vf[f], o[rt][f]);
          lsum[rt] = MFMA16x16(pf, onesf, lsum[rt]);
        }
      }
      __builtin_amdgcn_s_setprio(0);
    }

    __syncthreads();  // all waves done with Vl/Pl; K_{c+1} drained

    // issue V_{c+1} staging (lands during next QK+softmax)
    if (c + 1 < nch) {
#pragma unroll
      for (int it = 0; it < 4; ++it) {
        unsigned base = (unsigned)(it * 4 + wave) * 1024u;
        unsigned p = base + (unsigned)lane * 16u;
        unsigned row = p >> 7, col = p & 127u;
        unsigned gcol = col ^ ((row & 7u) << 4);
        async_copy16((const char*)(Vb + (size_t)row * 2048 + kc0 + 64) + gcol, Vl + base);
      }
    }
  }

  // epilogue
#pragma unroll
  for (int rt = 0; rt < 2; ++rt)
#pragma unroll
    for (int r = 0; r < 4; ++r) {
      float inv = 1.f / lsum[rt][r];
      int row = q0w + rt * 16 + lhi * 4 + r;
      size_t base = ((size_t)(b * 2048) + row) * 2048 + h * 128;
#pragma unroll
      for (int f = 0; f < 8; ++f)
        attnO[base + f * 16 + l16] = __float2bfloat16(o[rt][f][r] * inv);
    }
}

// ---------------- launch ----------------
extern "C" void kernel_launch(void* const* d_in, const int* in_sizes, int n_in,
                              void* d_out, int out_size, void* d_ws, size_t ws_size,
                              hipStream_t stream) {
  const float* hs = (const float*)d_in[0];
  const float* cosT = (const float*)d_in[2];
  const float* sinT = (const float*)d_in[3];
  const float* Wq = (const float*)d_in[4];
  const float* Wk = (const float*)d_in[5];
  const float* Wv = (const float*)d_in[6];
  const float* Wo = (const float*)d_in[7];
  const float* qw = (const float*)d_in[8];
  const float* kw = (const float*)d_in[9];
  float* out = (float*)d_out;

  char* ws = (char*)d_ws;
  size_t off = 0;
  auto alloc = [&](size_t bytes) {
    char* p = ws + off;
    off += (bytes + 255) & ~(size_t)255;
    return p;
  };
  bf16_t* hsb  = (bf16_t*)alloc((size_t)4096 * 2048 * 2);
  bf16_t* wqkv = (bf16_t*)alloc((size_t)3072 * 2048 * 2);
  bf16_t* wot  = (bf16_t*)alloc((size_t)2048 * 2048 * 2);
  float*  cqkv = (float*)alloc((size_t)4096 * 3072 * 4);
  bf16_t* qa   = (bf16_t*)alloc((size_t)2 * 16 * 2048 * 128 * 2);
  bf16_t* ka   = (bf16_t*)alloc((size_t)2 * 4 * 2048 * 128 * 2);
  bf16_t* vt   = (bf16_t*)alloc((size_t)2 * 4 * 2048 * 128 * 2);
  bf16_t* attn = (bf16_t*)cqkv;

  convbf_kernel<<<8192, 256, 0, stream>>>(hs, hsb, 2097152);
  dim3 tb(32, 8);
  wtrans_kernel<<<dim3(64, 64), tb, 0, stream>>>(Wq, wqkv, 2048, 0);
  wtrans_kernel<<<dim3(16, 64), tb, 0, stream>>>(Wk, wqkv, 512, 2048);
  wtrans_kernel<<<dim3(16, 64), tb, 0, stream>>>(Wv, wqkv, 512, 2560);
  wtrans_kernel<<<dim3(64, 64), tb, 0, stream>>>(Wo, wot, 2048, 0);
  gemm_bt_kernel<<<dim3(24, 32), 256, 0, stream>>>(hsb, wqkv, cqkv, 2048, 3072);
  qknorm_rope_kernel<<<20480, 256, 0, stream>>>(cqkv, cosT, sinT, qw, kw, qa, ka);
  vtrans_kernel<<<dim3(64, 4, 8), tb, 0, stream>>>(cqkv, vt);
  flash_kernel<<<512, 256, 0, stream>>>(qa, ka, vt, attn);
  gemm_bt_kernel<<<dim3(16, 32), 256, 0, stream>>>(attn, wot, out, 2048, 2048);
}

// Round 9
// 227.171 us; speedup vs baseline: 1.8527x; 1.1564x over previous
//
#include <hip/hip_runtime.h>
#include <hip/hip_bf16.h>
#include <stdint.h>

// Problem constants
// B=2, S=2048, HID=2048, NH=16, NKV=4, DH=128
// QKV fused GEMM: M=4096, K=2048, N=3072 (Q:0..2047, K:2048..2559, V:2560..3071)

typedef __attribute__((ext_vector_type(8))) short short8;
typedef __attribute__((ext_vector_type(4))) float floatx4;
typedef __hip_bfloat16 bf16_t;

#define MFMA16x16(a, b, c) __builtin_amdgcn_mfma_f32_16x16x32_bf16(a, b, c, 0, 0, 0)

__device__ __forceinline__ void async_copy16(const void* g, void* l) {
  __builtin_amdgcn_global_load_lds(
      (const __attribute__((address_space(1))) void*)g,
      (__attribute__((address_space(3))) void*)l, 16, 0, 0);
}

__device__ __forceinline__ unsigned short bf16bits(float x) {
  bf16_t h = __float2bfloat16(x);
  return *reinterpret_cast<unsigned short*>(&h);
}

// ---------------- f32 -> bf16 convert (vectorized) ----------------
__global__ __launch_bounds__(256) void convbf_kernel(const float* __restrict__ in,
                                                     bf16_t* __restrict__ out, int n4) {
  int i = blockIdx.x * 256 + threadIdx.x;
  if (i < n4) {
    const float4 v = reinterpret_cast<const float4*>(in)[i];
    ushort4 o;
    o.x = bf16bits(v.x); o.y = bf16bits(v.y); o.z = bf16bits(v.z); o.w = bf16bits(v.w);
    reinterpret_cast<ushort4*>(out)[i] = o;
  }
}

// ---------------- weight transpose f32[K][N] -> bf16[N][K], row offset ----------------
__global__ __launch_bounds__(256) void wtrans_kernel(const float* __restrict__ W,
                                                     bf16_t* __restrict__ Wt, int N, int roff) {
  __shared__ float t[32][33];
  int k0 = blockIdx.y * 32, n0 = blockIdx.x * 32;
#pragma unroll
  for (int j = 0; j < 4; ++j)
    t[threadIdx.y + j * 8][threadIdx.x] =
        W[(size_t)(k0 + threadIdx.y + j * 8) * N + n0 + threadIdx.x];
  __syncthreads();
#pragma unroll
  for (int j = 0; j < 4; ++j) {
    int n = n0 + threadIdx.y + j * 8, k = k0 + threadIdx.x;
    Wt[(size_t)(roff + n) * 2048 + k] = __float2bfloat16(t[threadIdx.x][threadIdx.y + j * 8]);
  }
}

// ---------------- GEMM: C[M][ldc](f32) = A[M][K](bf16) x Bt[N][K](bf16)^T ----------------
__global__ __launch_bounds__(256) void gemm_bt_kernel(const bf16_t* __restrict__ A,
                                                      const bf16_t* __restrict__ Bt,
                                                      float* __restrict__ C,
                                                      int K, int ldc) {
  __shared__ __align__(16) char smem[32768];
  const int tid = threadIdx.x;
  const int wave = tid >> 6, lane = tid & 63;
  const int wr = wave >> 1, wc = wave & 1;
  const int l16 = lane & 15, lhi = lane >> 4;
  const int bm = blockIdx.y * 128, bn = blockIdx.x * 128;

  floatx4 acc[4][4] = {};

  for (int k0 = 0; k0 < K; k0 += 64) {
    __syncthreads();
#pragma unroll
    for (int i = 0; i < 4; ++i) {
      int chunk = i * 4 + wave;
      unsigned p = (unsigned)chunk * 1024u + (unsigned)lane * 16u;
      unsigned row = p >> 7;
      unsigned colg = (p & 127u) ^ ((row & 7u) << 4);
      const char* gA = (const char*)(A + (size_t)(bm + row) * K + k0) + colg;
      async_copy16(gA, smem + (size_t)chunk * 1024);
      const char* gB = (const char*)(Bt + (size_t)(bn + row) * K + k0) + colg;
      async_copy16(gB, smem + 16384 + (size_t)chunk * 1024);
    }
    __syncthreads();
#pragma unroll
    for (int kk = 0; kk < 2; ++kk) {
      short8 fa[4], fb[4];
#pragma unroll
      for (int mi = 0; mi < 4; ++mi) {
        unsigned row = wr * 64 + mi * 16 + l16;
        unsigned off = row * 128u + kk * 64u + lhi * 16u;
        off ^= (row & 7u) << 4;
        fa[mi] = *(const short8*)(smem + off);
      }
#pragma unroll
      for (int ni = 0; ni < 4; ++ni) {
        unsigned row = wc * 64 + ni * 16 + l16;
        unsigned off = row * 128u + kk * 64u + lhi * 16u;
        off ^= (row & 7u) << 4;
        fb[ni] = *(const short8*)(smem + 16384 + off);
      }
#pragma unroll
      for (int mi = 0; mi < 4; ++mi)
#pragma unroll
        for (int ni = 0; ni < 4; ++ni)
          acc[mi][ni] = MFMA16x16(fa[mi], fb[ni], acc[mi][ni]);
    }
  }
#pragma unroll
  for (int mi = 0; mi < 4; ++mi)
#pragma unroll
    for (int ni = 0; ni < 4; ++ni)
#pragma unroll
      for (int r = 0; r < 4; ++r) {
        int row = bm + wr * 64 + mi * 16 + lhi * 4 + r;
        int col = bn + wc * 64 + ni * 16 + l16;
        C[(size_t)row * ldc + col] = acc[mi][ni][r];
      }
}

// ---------------- RMSNorm + RoPE + relayout for Q and K ----------------
// Q additionally pre-scaled by 1/sqrt(DH) so flash drops the scale multiply.
__global__ __launch_bounds__(256) void qknorm_rope_kernel(
    const float* __restrict__ Cqkv, const float* __restrict__ cosT,
    const float* __restrict__ sinT, const float* __restrict__ qw,
    const float* __restrict__ kw, bf16_t* __restrict__ Qa, bf16_t* __restrict__ Ka) {
  int wave = threadIdx.x >> 6, lane = threadIdx.x & 63;
  int task = blockIdx.x * 4 + wave;
  int unit = task % 20;
  int row = task / 20;
  int b = row >> 11, s = row & 2047;
  const float* src;
  const float* w;
  bf16_t* dst;
  float sc;
  if (unit < 16) {
    src = Cqkv + (size_t)row * 3072 + unit * 128;
    w = qw;
    dst = Qa + ((size_t)(b * 16 + unit) * 2048 + s) * 128;
    sc = 0.088388347648318447f;  // 1/sqrt(128)
  } else {
    int kh = unit - 16;
    src = Cqkv + (size_t)row * 3072 + 2048 + kh * 128;
    w = kw;
    dst = Ka + ((size_t)(b * 4 + kh) * 2048 + s) * 128;
    sc = 1.0f;
  }
  float x1 = src[lane], x2 = src[lane + 64];
  float ss = x1 * x1 + x2 * x2;
#pragma unroll
  for (int off = 1; off < 64; off <<= 1) ss += __shfl_xor(ss, off, 64);
  float inv = rsqrtf(ss * (1.f / 128.f) + 1e-6f);
  x1 = x1 * inv * w[lane];
  x2 = x2 * inv * w[lane + 64];
  float c1 = cosT[(size_t)s * 128 + lane], c2 = cosT[(size_t)s * 128 + lane + 64];
  float s1 = sinT[(size_t)s * 128 + lane], s2 = sinT[(size_t)s * 128 + lane + 64];
  dst[lane] = __float2bfloat16((x1 * c1 - x2 * s1) * sc);
  dst[lane + 64] = __float2bfloat16((x2 * c2 + x1 * s2) * sc);
}

// ---------------- V transpose: Cqkv f32 -> Vt[b][kh][d][s] bf16 ----------------
__global__ __launch_bounds__(256) void vtrans_kernel(const float* __restrict__ Cqkv,
                                                     bf16_t* __restrict__ Vt) {
  __shared__ float t[32][33];
  int bk = blockIdx.z;
  int b = bk >> 2, kh = bk & 3;
  int s0 = blockIdx.x * 32, d0 = blockIdx.y * 32;
  const float* src = Cqkv + (size_t)(b * 2048) * 3072 + 2560 + kh * 128;
#pragma unroll
  for (int j = 0; j < 4; ++j)
    t[threadIdx.y + j * 8][threadIdx.x] =
        src[(size_t)(s0 + threadIdx.y + j * 8) * 3072 + d0 + threadIdx.x];
  __syncthreads();
  bf16_t* dst = Vt + (size_t)(b * 4 + kh) * 128 * 2048;
#pragma unroll
  for (int j = 0; j < 4; ++j) {
    int d = d0 + threadIdx.y + j * 8, s = s0 + threadIdx.x;
    dst[(size_t)d * 2048 + s] = __float2bfloat16(t[threadIdx.x][threadIdx.y + j * 8]);
  }
}

// swizzle: 3-bit XOR field in bits 4-6 of the byte offset; uses row bits 0-2 and 3-4
// so K-fragment rows (only 4 distinct row&7 under keymap) still spread 8 ways.
__device__ __forceinline__ unsigned swz_row(unsigned row) {
  return (((row & 7u) ^ ((row >> 3) << 1)) & 7u) << 4;
}

// ---------------- Flash attention v5 (causal, GQA): in-register softmax ----------------
// Swapped QK^T: mfma(K,Q) with key-permuted K fragments (keymap) so each lane owns
// one q-row and its 16 scores land exactly in PV A-fragment key slots. P never
// touches LDS; row-max = 15 in-lane fmax + 2 shfl_xor; defer-max state is scalar.
// LDS 32KB: K[64][256B] + V^T[128][128B], both new-swizzle, staged via
// global_load_lds w16 (pipeline as v4: K staged during PV, V during QK+softmax).
__global__ __launch_bounds__(256, 2) void flash_kernel(const bf16_t* __restrict__ Qa,
                                                       const bf16_t* __restrict__ Ka,
                                                       const bf16_t* __restrict__ Vt,
                                                       bf16_t* __restrict__ attnO) {
  __shared__ __align__(16) char smem[32768];
  const int tid = threadIdx.x;
  const int wave = tid >> 6, lane = tid & 63;
  const int l16 = lane & 15, lhi = lane >> 4;
  const int bid = blockIdx.x;          // 512 blocks
  const int bh = bid & 31;             // b*16 + h
  const int ib = bid >> 5;             // 0..15
  const int qb = (ib < 8) ? (15 - ib) : (ib - 8);  // heavy 15..8, then light 0..7
  const int h = bh & 15, b = bh >> 4;
  const int kh = h >> 2;
  const int q0b = qb << 7;
  const int q0w = q0b + wave * 32;

  const bf16_t* Qb = Qa + ((size_t)bh * 2048 + q0w) * 128;
  const bf16_t* Kb = Ka + (size_t)(b * 4 + kh) * 2048 * 128;
  const bf16_t* Vb = Vt + (size_t)(b * 4 + kh) * 128 * 2048;

  char* Kl = smem;          // [64 keys][256B] swizzled
  char* Vl = smem + 16384;  // [128 d][128B] swizzled

  // Q fragments (B-operand): lane: q-col rt*16+l16, d-slots kk*32+lhi*8+j
  short8 qf[2][4];
#pragma unroll
  for (int rt = 0; rt < 2; ++rt)
#pragma unroll
    for (int kk = 0; kk < 4; ++kk)
      qf[rt][kk] = *(const short8*)(Qb + (size_t)(rt * 16 + l16) * 128 + kk * 32 + lhi * 8);

  short8 onesf;
#pragma unroll
  for (int j = 0; j < 8; ++j) onesf[j] = (short)0x3F80;  // bf16 1.0

  floatx4 o[2][8] = {};    // O rows lhi*4+r (+rt*16), cols f*16+l16
  floatx4 lsum[2] = {};    // same C layout
  short8 pf[2][2];         // P A-frags: [rt][ks]
  float m[2] = {-1e30f, -1e30f};  // per-lane running max for q = q0w+rt*16+l16

  const float THR = 8.0f;
  const int nch = 2 * qb + 2;

  // prologue: stage K_0 and V_0
#pragma unroll
  for (int it = 0; it < 4; ++it) {
    unsigned p = (unsigned)(it * 4 + wave) * 1024u + (unsigned)lane * 16u;
    unsigned row = p >> 8;
    unsigned gcol = (p & 255u) ^ swz_row(row);
    async_copy16((const char*)(Kb + (size_t)row * 128) + gcol,
                 smem + (size_t)(it * 4 + wave) * 1024);
  }
#pragma unroll
  for (int it = 0; it < 4; ++it) {
    unsigned p = (unsigned)(it * 4 + wave) * 1024u + (unsigned)lane * 16u;
    unsigned row = p >> 7;
    unsigned gcol = (p & 127u) ^ swz_row(row);
    async_copy16((const char*)(Vb + (size_t)row * 2048) + gcol,
                 Vl + (size_t)(it * 4 + wave) * 1024);
  }
  __syncthreads();

  for (int c = 0; c < nch; ++c) {
    const int kc0 = c << 6;
    const bool active = (kc0 <= q0w + 31);

    if (active) {
      // QK^T (swapped): s[rt][g] C-layout: q-col = l16, key = keymap_g(lhi*4+r)
      floatx4 s[2][4] = {};
      __builtin_amdgcn_s_setprio(1);
#pragma unroll
      for (int g = 0; g < 4; ++g) {
        unsigned row = (unsigned)(l16 >> 2) * 8u + (unsigned)((g & 1) * 4) +
                       (unsigned)(l16 & 3) + (unsigned)((g >> 1) * 32);
        unsigned base = row * 256u;
        unsigned px = swz_row(row);
#pragma unroll
        for (int kk = 0; kk < 4; ++kk) {
          short8 kf = *(const short8*)(Kl + base + (((unsigned)(kk * 64 + lhi * 16)) ^ px));
          s[0][g] = MFMA16x16(kf, qf[0][kk], s[0][g]);
          s[1][g] = MFMA16x16(kf, qf[1][kk], s[1][g]);
        }
      }
      __builtin_amdgcn_s_setprio(0);

      const bool needMask = (kc0 + 64 > q0w);
#pragma unroll
      for (int rt = 0; rt < 2; ++rt) {
        const int qrow = q0w + rt * 16 + l16;
        if (needMask) {
#pragma unroll
          for (int g = 0; g < 4; ++g)
#pragma unroll
            for (int r = 0; r < 4; ++r) {
              int key = kc0 + lhi * 8 + (g & 1) * 4 + r + (g >> 1) * 32;
              if (key > qrow) s[rt][g][r] = -1e9f;
            }
        }
        // row max: in-lane over 16, then across the 4 lhi groups
        float mx = s[rt][0][0];
#pragma unroll
        for (int g = 0; g < 4; ++g)
#pragma unroll
          for (int r = 0; r < 4; ++r) mx = fmaxf(mx, s[rt][g][r]);
        mx = fmaxf(mx, __shfl_xor(mx, 16, 64));
        mx = fmaxf(mx, __shfl_xor(mx, 32, 64));
        bool grow = mx > m[rt] + THR;
        if (__any(grow)) {
          float mn = fmaxf(m[rt], mx);
          float corr = __expf(m[rt] - mn);
          m[rt] = mn;
#pragma unroll
          for (int r = 0; r < 4; ++r) {
            float co = __shfl(corr, lhi * 4 + r, 64);  // softmax layout -> O layout
            lsum[rt][r] *= co;
#pragma unroll
            for (int f = 0; f < 8; ++f) o[rt][f][r] *= co;
          }
        }
        // p = exp(s - m), pack to PV A-frags fully in-register
#pragma unroll
        for (int ks = 0; ks < 2; ++ks) {
          union { unsigned u[4]; short8 v; } pk;
#pragma unroll
          for (int half = 0; half < 2; ++half) {
            int g = ks * 2 + half;
            float p0 = __expf(s[rt][g][0] - m[rt]);
            float p1 = __expf(s[rt][g][1] - m[rt]);
            float p2 = __expf(s[rt][g][2] - m[rt]);
            float p3 = __expf(s[rt][g][3] - m[rt]);
            pk.u[half * 2] = (unsigned)bf16bits(p0) | ((unsigned)bf16bits(p1) << 16);
            pk.u[half * 2 + 1] = (unsigned)bf16bits(p2) | ((unsigned)bf16bits(p3) << 16);
          }
          pf[rt][ks] = pk.v;
        }
      }
    }

    __syncthreads();  // QK done (K free), V_c staging drained

    // issue K_{c+1} staging (lands during PV)
    if (c + 1 < nch) {
#pragma unroll
      for (int it = 0; it < 4; ++it) {
        unsigned p = (unsigned)(it * 4 + wave) * 1024u + (unsigned)lane * 16u;
        unsigned row = p >> 8;
        unsigned gcol = (p & 255u) ^ swz_row(row);
        async_copy16((const char*)(Kb + (size_t)(kc0 + 64 + row) * 128) + gcol,
                     Kl + (size_t)(it * 4 + wave) * 1024);
      }
    }

    if (active) {
      // PV + ones-column row-sum (pf in registers)
      __builtin_amdgcn_s_setprio(1);
#pragma unroll
      for (int ks = 0; ks < 2; ++ks) {
#pragma unroll
        for (int f = 0; f < 8; ++f) {
          unsigned row = (unsigned)(f * 16 + l16);
          short8 vf = *(const short8*)(Vl + row * 128u +
                                       (((unsigned)(ks * 64 + lhi * 16)) ^ swz_row(row)));
          o[0][f] = MFMA16x16(pf[0][ks], vf, o[0][f]);
          o[1][f] = MFMA16x16(pf[1][ks], vf, o[1][f]);
        }
        lsum[0] = MFMA16x16(pf[0][ks], onesf, lsum[0]);
        lsum[1] = MFMA16x16(pf[1][ks], onesf, lsum[1]);
      }
      __builtin_amdgcn_s_setprio(0);
    }

    __syncthreads();  // PV done (V free), K_{c+1} staging drained

    // issue V_{c+1} staging (lands during next QK+softmax)
    if (c + 1 < nch) {
#pragma unroll
      for (int it = 0; it < 4; ++it) {
        unsigned p = (unsigned)(it * 4 + wave) * 1024u + (unsigned)lane * 16u;
        unsigned row = p >> 7;
        unsigned gcol = (p & 127u) ^ swz_row(row);
        async_copy16((const char*)(Vb + (size_t)row * 2048 + kc0 + 64) + gcol,
                     Vl + (size_t)(it * 4 + wave) * 1024);
      }
    }
  }

  // epilogue: O rows = q0w + rt*16 + lhi*4 + r, cols f*16 + l16
#pragma unroll
  for (int rt = 0; rt < 2; ++rt)
#pragma unroll
    for (int r = 0; r < 4; ++r) {
      float inv = 1.f / lsum[rt][r];
      int row = q0w + rt * 16 + lhi * 4 + r;
      size_t base = ((size_t)(b * 2048) + row) * 2048 + h * 128;
#pragma unroll
      for (int f = 0; f < 8; ++f)
        attnO[base + f * 16 + l16] = __float2bfloat16(o[rt][f][r] * inv);
    }
}

// ---------------- launch ----------------
extern "C" void kernel_launch(void* const* d_in, const int* in_sizes, int n_in,
                              void* d_out, int out_size, void* d_ws, size_t ws_size,
                              hipStream_t stream) {
  const float* hs = (const float*)d_in[0];
  const float* cosT = (const float*)d_in[2];
  const float* sinT = (const float*)d_in[3];
  const float* Wq = (const float*)d_in[4];
  const float* Wk = (const float*)d_in[5];
  const float* Wv = (const float*)d_in[6];
  const float* Wo = (const float*)d_in[7];
  const float* qw = (const float*)d_in[8];
  const float* kw = (const float*)d_in[9];
  float* out = (float*)d_out;

  char* ws = (char*)d_ws;
  size_t off = 0;
  auto alloc = [&](size_t bytes) {
    char* p = ws + off;
    off += (bytes + 255) & ~(size_t)255;
    return p;
  };
  bf16_t* hsb  = (bf16_t*)alloc((size_t)4096 * 2048 * 2);
  bf16_t* wqkv = (bf16_t*)alloc((size_t)3072 * 2048 * 2);
  bf16_t* wot  = (bf16_t*)alloc((size_t)2048 * 2048 * 2);
  float*  cqkv = (float*)alloc((size_t)4096 * 3072 * 4);
  bf16_t* qa   = (bf16_t*)alloc((size_t)2 * 16 * 2048 * 128 * 2);
  bf16_t* ka   = (bf16_t*)alloc((size_t)2 * 4 * 2048 * 128 * 2);
  bf16_t* vt   = (bf16_t*)alloc((size_t)2 * 4 * 2048 * 128 * 2);
  bf16_t* attn = (bf16_t*)cqkv;

  convbf_kernel<<<8192, 256, 0, stream>>>(hs, hsb, 2097152);
  dim3 tb(32, 8);
  wtrans_kernel<<<dim3(64, 64), tb, 0, stream>>>(Wq, wqkv, 2048, 0);
  wtrans_kernel<<<dim3(16, 64), tb, 0, stream>>>(Wk, wqkv, 512, 2048);
  wtrans_kernel<<<dim3(16, 64), tb, 0, stream>>>(Wv, wqkv, 512, 2560);
  wtrans_kernel<<<dim3(64, 64), tb, 0, stream>>>(Wo, wot, 2048, 0);
  gemm_bt_kernel<<<dim3(24, 32), 256, 0, stream>>>(hsb, wqkv, cqkv, 2048, 3072);
  qknorm_rope_kernel<<<20480, 256, 0, stream>>>(cqkv, cosT, sinT, qw, kw, qa, ka);
  vtrans_kernel<<<dim3(64, 4, 8), tb, 0, stream>>>(cqkv, vt);
  flash_kernel<<<512, 256, 0, stream>>>(qa, ka, vt, attn);
  gemm_bt_kernel<<<dim3(16, 32), 256, 0, stream>>>(attn, wot, out, 2048, 2048);
}

// Round 10
// 196.517 us; speedup vs baseline: 2.1417x; 1.1560x over previous
//
#include <hip/hip_runtime.h>
#include <hip/hip_bf16.h>
#include <stdint.h>

// Problem constants
// B=2, S=2048, HID=2048, NH=16, NKV=4, DH=128
// QKV fused GEMM: M=4096, K=2048, N=3072 (Q:0..2047, K:2048..2559, V:2560..3071)

typedef __attribute__((ext_vector_type(8))) short short8;
typedef __attribute__((ext_vector_type(4))) float floatx4;
typedef __hip_bfloat16 bf16_t;

#define MFMA16x16(a, b, c) __builtin_amdgcn_mfma_f32_16x16x32_bf16(a, b, c, 0, 0, 0)

__device__ __forceinline__ void async_copy16(const void* g, void* l) {
  __builtin_amdgcn_global_load_lds(
      (const __attribute__((address_space(1))) void*)g,
      (__attribute__((address_space(3))) void*)l, 16, 0, 0);
}

__device__ __forceinline__ unsigned short bf16bits(float x) {
  bf16_t h = __float2bfloat16(x);
  return *reinterpret_cast<unsigned short*>(&h);
}

// ---------------- f32 -> bf16 convert (vectorized) ----------------
__global__ __launch_bounds__(256) void convbf_kernel(const float* __restrict__ in,
                                                     bf16_t* __restrict__ out, int n4) {
  int i = blockIdx.x * 256 + threadIdx.x;
  if (i < n4) {
    const float4 v = reinterpret_cast<const float4*>(in)[i];
    ushort4 o;
    o.x = bf16bits(v.x); o.y = bf16bits(v.y); o.z = bf16bits(v.z); o.w = bf16bits(v.w);
    reinterpret_cast<ushort4*>(out)[i] = o;
  }
}

// ---------------- weight transpose f32[K][N] -> bf16[N][K], row offset ----------------
__global__ __launch_bounds__(256) void wtrans_kernel(const float* __restrict__ W,
                                                     bf16_t* __restrict__ Wt, int N, int roff) {
  __shared__ float t[32][33];
  int k0 = blockIdx.y * 32, n0 = blockIdx.x * 32;
#pragma unroll
  for (int j = 0; j < 4; ++j)
    t[threadIdx.y + j * 8][threadIdx.x] =
        W[(size_t)(k0 + threadIdx.y + j * 8) * N + n0 + threadIdx.x];
  __syncthreads();
#pragma unroll
  for (int j = 0; j < 4; ++j) {
    int n = n0 + threadIdx.y + j * 8, k = k0 + threadIdx.x;
    Wt[(size_t)(roff + n) * 2048 + k] = __float2bfloat16(t[threadIdx.x][threadIdx.y + j * 8]);
  }
}

// ---------------- GEMM: C[M][ldc] = A[M][K](bf16) x Bt[N][K](bf16)^T ----------------
// 128x128 tile, BK=64, 3 blocks/CU (VGPR 96 << 170 cap, LDS 96KB/CU).
// T1 bijective XCD swizzle (grids are %8==0). OBF=1 writes bf16 C, else f32.
template <int OBF>
__global__ __launch_bounds__(256, 3) void gemm_bt_kernel(const bf16_t* __restrict__ A,
                                                         const bf16_t* __restrict__ Bt,
                                                         void* __restrict__ Cv,
                                                         int K, int ldc) {
  __shared__ __align__(16) char smem[32768];
  const int tid = threadIdx.x;
  const int wave = tid >> 6, lane = tid & 63;
  const int wr = wave >> 1, wc = wave & 1;
  const int l16 = lane & 15, lhi = lane >> 4;

  // XCD-aware remap of the flattened grid (nwg % 8 == 0 for both launches)
  const int nwg = gridDim.x * gridDim.y;
  const int orig = blockIdx.y * gridDim.x + blockIdx.x;
  const int swz = (orig & 7) * (nwg >> 3) + (orig >> 3);
  const int bn = (swz % gridDim.x) * 128;
  const int bm = (swz / gridDim.x) * 128;

  floatx4 acc[4][4] = {};

  for (int k0 = 0; k0 < K; k0 += 64) {
    __syncthreads();
#pragma unroll
    for (int i = 0; i < 4; ++i) {
      int chunk = i * 4 + wave;
      unsigned p = (unsigned)chunk * 1024u + (unsigned)lane * 16u;
      unsigned row = p >> 7;
      unsigned colg = (p & 127u) ^ ((row & 7u) << 4);
      const char* gA = (const char*)(A + (size_t)(bm + row) * K + k0) + colg;
      async_copy16(gA, smem + (size_t)chunk * 1024);
      const char* gB = (const char*)(Bt + (size_t)(bn + row) * K + k0) + colg;
      async_copy16(gB, smem + 16384 + (size_t)chunk * 1024);
    }
    __syncthreads();
#pragma unroll
    for (int kk = 0; kk < 2; ++kk) {
      short8 fa[4], fb[4];
#pragma unroll
      for (int mi = 0; mi < 4; ++mi) {
        unsigned row = wr * 64 + mi * 16 + l16;
        unsigned off = row * 128u + kk * 64u + lhi * 16u;
        off ^= (row & 7u) << 4;
        fa[mi] = *(const short8*)(smem + off);
      }
#pragma unroll
      for (int ni = 0; ni < 4; ++ni) {
        unsigned row = wc * 64 + ni * 16 + l16;
        unsigned off = row * 128u + kk * 64u + lhi * 16u;
        off ^= (row & 7u) << 4;
        fb[ni] = *(const short8*)(smem + 16384 + off);
      }
#pragma unroll
      for (int mi = 0; mi < 4; ++mi)
#pragma unroll
        for (int ni = 0; ni < 4; ++ni)
          acc[mi][ni] = MFMA16x16(fa[mi], fb[ni], acc[mi][ni]);
    }
  }
#pragma unroll
  for (int mi = 0; mi < 4; ++mi)
#pragma unroll
    for (int ni = 0; ni < 4; ++ni)
#pragma unroll
      for (int r = 0; r < 4; ++r) {
        int row = bm + wr * 64 + mi * 16 + lhi * 4 + r;
        int col = bn + wc * 64 + ni * 16 + l16;
        if (OBF)
          ((bf16_t*)Cv)[(size_t)row * ldc + col] = __float2bfloat16(acc[mi][ni][r]);
        else
          ((float*)Cv)[(size_t)row * ldc + col] = acc[mi][ni][r];
      }
}

// ---------------- RMSNorm + RoPE + relayout for Q and K (bf16 input) ----------------
// Q additionally pre-scaled by 1/sqrt(DH) so flash drops the scale multiply.
__global__ __launch_bounds__(256) void qknorm_rope_kernel(
    const bf16_t* __restrict__ Cqkv, const float* __restrict__ cosT,
    const float* __restrict__ sinT, const float* __restrict__ qw,
    const float* __restrict__ kw, bf16_t* __restrict__ Qa, bf16_t* __restrict__ Ka) {
  int wave = threadIdx.x >> 6, lane = threadIdx.x & 63;
  int task = blockIdx.x * 4 + wave;
  int unit = task % 20;
  int row = task / 20;
  int b = row >> 11, s = row & 2047;
  const bf16_t* src;
  const float* w;
  bf16_t* dst;
  float sc;
  if (unit < 16) {
    src = Cqkv + (size_t)row * 3072 + unit * 128;
    w = qw;
    dst = Qa + ((size_t)(b * 16 + unit) * 2048 + s) * 128;
    sc = 0.088388347648318447f;  // 1/sqrt(128)
  } else {
    int kh = unit - 16;
    src = Cqkv + (size_t)row * 3072 + 2048 + kh * 128;
    w = kw;
    dst = Ka + ((size_t)(b * 4 + kh) * 2048 + s) * 128;
    sc = 1.0f;
  }
  float x1 = __bfloat162float(src[lane]), x2 = __bfloat162float(src[lane + 64]);
  float ss = x1 * x1 + x2 * x2;
#pragma unroll
  for (int off = 1; off < 64; off <<= 1) ss += __shfl_xor(ss, off, 64);
  float inv = rsqrtf(ss * (1.f / 128.f) + 1e-6f);
  x1 = x1 * inv * w[lane];
  x2 = x2 * inv * w[lane + 64];
  float c1 = cosT[(size_t)s * 128 + lane], c2 = cosT[(size_t)s * 128 + lane + 64];
  float s1 = sinT[(size_t)s * 128 + lane], s2 = sinT[(size_t)s * 128 + lane + 64];
  dst[lane] = __float2bfloat16((x1 * c1 - x2 * s1) * sc);
  dst[lane + 64] = __float2bfloat16((x2 * c2 + x1 * s2) * sc);
}

// ---------------- V transpose: Cqkv bf16 -> Vt[b][kh][d][s] bf16 ----------------
__global__ __launch_bounds__(256) void vtrans_kernel(const bf16_t* __restrict__ Cqkv,
                                                     bf16_t* __restrict__ Vt) {
  __shared__ bf16_t t[32][33];
  int bk = blockIdx.z;
  int b = bk >> 2, kh = bk & 3;
  int s0 = blockIdx.x * 32, d0 = blockIdx.y * 32;
  const bf16_t* src = Cqkv + (size_t)(b * 2048) * 3072 + 2560 + kh * 128;
#pragma unroll
  for (int j = 0; j < 4; ++j)
    t[threadIdx.y + j * 8][threadIdx.x] =
        src[(size_t)(s0 + threadIdx.y + j * 8) * 3072 + d0 + threadIdx.x];
  __syncthreads();
  bf16_t* dst = Vt + (size_t)(b * 4 + kh) * 128 * 2048;
#pragma unroll
  for (int j = 0; j < 4; ++j) {
    int d = d0 + threadIdx.y + j * 8, s = s0 + threadIdx.x;
    dst[(size_t)d * 2048 + s] = t[threadIdx.x][threadIdx.y + j * 8];
  }
}

// swizzle: 3-bit XOR field in bits 4-6 of the byte offset; uses row bits 0-2 and 3-4
// so K-fragment rows (only 4 distinct row&7 under keymap) still spread 8 ways.
__device__ __forceinline__ unsigned swz_row(unsigned row) {
  return (((row & 7u) ^ ((row >> 3) << 1)) & 7u) << 4;
}

// ---------------- Flash attention v5 (causal, GQA): in-register softmax ----------------
// Swapped QK^T: mfma(K,Q) with key-permuted K fragments (keymap) so each lane owns
// one q-row and its 16 scores land exactly in PV A-fragment key slots. P never
// touches LDS; row-max = 15 in-lane fmax + 2 shfl_xor; defer-max state is scalar.
// LDS 32KB: K[64][256B] + V^T[128][128B], both new-swizzle, staged via
// global_load_lds w16 (pipeline as v4: K staged during PV, V during QK+softmax).
__global__ __launch_bounds__(256, 2) void flash_kernel(const bf16_t* __restrict__ Qa,
                                                       const bf16_t* __restrict__ Ka,
                                                       const bf16_t* __restrict__ Vt,
                                                       bf16_t* __restrict__ attnO) {
  __shared__ __align__(16) char smem[32768];
  const int tid = threadIdx.x;
  const int wave = tid >> 6, lane = tid & 63;
  const int l16 = lane & 15, lhi = lane >> 4;
  const int bid = blockIdx.x;          // 512 blocks
  const int bh = bid & 31;             // b*16 + h
  const int ib = bid >> 5;             // 0..15
  const int qb = (ib < 8) ? (15 - ib) : (ib - 8);  // heavy 15..8, then light 0..7
  const int h = bh & 15, b = bh >> 4;
  const int kh = h >> 2;
  const int q0b = qb << 7;
  const int q0w = q0b + wave * 32;

  const bf16_t* Qb = Qa + ((size_t)bh * 2048 + q0w) * 128;
  const bf16_t* Kb = Ka + (size_t)(b * 4 + kh) * 2048 * 128;
  const bf16_t* Vb = Vt + (size_t)(b * 4 + kh) * 128 * 2048;

  char* Kl = smem;          // [64 keys][256B] swizzled
  char* Vl = smem + 16384;  // [128 d][128B] swizzled

  // Q fragments (B-operand): lane: q-col rt*16+l16, d-slots kk*32+lhi*8+j
  short8 qf[2][4];
#pragma unroll
  for (int rt = 0; rt < 2; ++rt)
#pragma unroll
    for (int kk = 0; kk < 4; ++kk)
      qf[rt][kk] = *(const short8*)(Qb + (size_t)(rt * 16 + l16) * 128 + kk * 32 + lhi * 8);

  short8 onesf;
#pragma unroll
  for (int j = 0; j < 8; ++j) onesf[j] = (short)0x3F80;  // bf16 1.0

  floatx4 o[2][8] = {};    // O rows lhi*4+r (+rt*16), cols f*16+l16
  floatx4 lsum[2] = {};    // same C layout
  short8 pf[2][2];         // P A-frags: [rt][ks]
  float m[2] = {-1e30f, -1e30f};  // per-lane running max for q = q0w+rt*16+l16

  const float THR = 8.0f;
  const int nch = 2 * qb + 2;

  // prologue: stage K_0 and V_0
#pragma unroll
  for (int it = 0; it < 4; ++it) {
    unsigned p = (unsigned)(it * 4 + wave) * 1024u + (unsigned)lane * 16u;
    unsigned row = p >> 8;
    unsigned gcol = (p & 255u) ^ swz_row(row);
    async_copy16((const char*)(Kb + (size_t)row * 128) + gcol,
                 smem + (size_t)(it * 4 + wave) * 1024);
  }
#pragma unroll
  for (int it = 0; it < 4; ++it) {
    unsigned p = (unsigned)(it * 4 + wave) * 1024u + (unsigned)lane * 16u;
    unsigned row = p >> 7;
    unsigned gcol = (p & 127u) ^ swz_row(row);
    async_copy16((const char*)(Vb + (size_t)row * 2048) + gcol,
                 Vl + (size_t)(it * 4 + wave) * 1024);
  }
  __syncthreads();

  for (int c = 0; c < nch; ++c) {
    const int kc0 = c << 6;
    const bool active = (kc0 <= q0w + 31);

    if (active) {
      // QK^T (swapped): s[rt][g] C-layout: q-col = l16, key = keymap_g(lhi*4+r)
      floatx4 s[2][4] = {};
      __builtin_amdgcn_s_setprio(1);
#pragma unroll
      for (int g = 0; g < 4; ++g) {
        unsigned row = (unsigned)(l16 >> 2) * 8u + (unsigned)((g & 1) * 4) +
                       (unsigned)(l16 & 3) + (unsigned)((g >> 1) * 32);
        unsigned base = row * 256u;
        unsigned px = swz_row(row);
#pragma unroll
        for (int kk = 0; kk < 4; ++kk) {
          short8 kf = *(const short8*)(Kl + base + (((unsigned)(kk * 64 + lhi * 16)) ^ px));
          s[0][g] = MFMA16x16(kf, qf[0][kk], s[0][g]);
          s[1][g] = MFMA16x16(kf, qf[1][kk], s[1][g]);
        }
      }
      __builtin_amdgcn_s_setprio(0);

      const bool needMask = (kc0 + 64 > q0w);
#pragma unroll
      for (int rt = 0; rt < 2; ++rt) {
        const int qrow = q0w + rt * 16 + l16;
        if (needMask) {
#pragma unroll
          for (int g = 0; g < 4; ++g)
#pragma unroll
            for (int r = 0; r < 4; ++r) {
              int key = kc0 + lhi * 8 + (g & 1) * 4 + r + (g >> 1) * 32;
              if (key > qrow) s[rt][g][r] = -1e9f;
            }
        }
        // row max: in-lane over 16, then across the 4 lhi groups
        float mx = s[rt][0][0];
#pragma unroll
        for (int g = 0; g < 4; ++g)
#pragma unroll
          for (int r = 0; r < 4; ++r) mx = fmaxf(mx, s[rt][g][r]);
        mx = fmaxf(mx, __shfl_xor(mx, 16, 64));
        mx = fmaxf(mx, __shfl_xor(mx, 32, 64));
        bool grow = mx > m[rt] + THR;
        if (__any(grow)) {
          float mn = fmaxf(m[rt], mx);
          float corr = __expf(m[rt] - mn);
          m[rt] = mn;
#pragma unroll
          for (int r = 0; r < 4; ++r) {
            float co = __shfl(corr, lhi * 4 + r, 64);  // softmax layout -> O layout
            lsum[rt][r] *= co;
#pragma unroll
            for (int f = 0; f < 8; ++f) o[rt][f][r] *= co;
          }
        }
        // p = exp(s - m), pack to PV A-frags fully in-register
#pragma unroll
        for (int ks = 0; ks < 2; ++ks) {
          union { unsigned u[4]; short8 v; } pk;
#pragma unroll
          for (int half = 0; half < 2; ++half) {
            int g = ks * 2 + half;
            float p0 = __expf(s[rt][g][0] - m[rt]);
            float p1 = __expf(s[rt][g][1] - m[rt]);
            float p2 = __expf(s[rt][g][2] - m[rt]);
            float p3 = __expf(s[rt][g][3] - m[rt]);
            pk.u[half * 2] = (unsigned)bf16bits(p0) | ((unsigned)bf16bits(p1) << 16);
            pk.u[half * 2 + 1] = (unsigned)bf16bits(p2) | ((unsigned)bf16bits(p3) << 16);
          }
          pf[rt][ks] = pk.v;
        }
      }
    }

    __syncthreads();  // QK done (K free), V_c staging drained

    // issue K_{c+1} staging (lands during PV)
    if (c + 1 < nch) {
#pragma unroll
      for (int it = 0; it < 4; ++it) {
        unsigned p = (unsigned)(it * 4 + wave) * 1024u + (unsigned)lane * 16u;
        unsigned row = p >> 8;
        unsigned gcol = (p & 255u) ^ swz_row(row);
        async_copy16((const char*)(Kb + (size_t)(kc0 + 64 + row) * 128) + gcol,
                     Kl + (size_t)(it * 4 + wave) * 1024);
      }
    }

    if (active) {
      // PV + ones-column row-sum (pf in registers)
      __builtin_amdgcn_s_setprio(1);
#pragma unroll
      for (int ks = 0; ks < 2; ++ks) {
#pragma unroll
        for (int f = 0; f < 8; ++f) {
          unsigned row = (unsigned)(f * 16 + l16);
          short8 vf = *(const short8*)(Vl + row * 128u +
                                       (((unsigned)(ks * 64 + lhi * 16)) ^ swz_row(row)));
          o[0][f] = MFMA16x16(pf[0][ks], vf, o[0][f]);
          o[1][f] = MFMA16x16(pf[1][ks], vf, o[1][f]);
        }
        lsum[0] = MFMA16x16(pf[0][ks], onesf, lsum[0]);
        lsum[1] = MFMA16x16(pf[1][ks], onesf, lsum[1]);
      }
      __builtin_amdgcn_s_setprio(0);
    }

    __syncthreads();  // PV done (V free), K_{c+1} staging drained

    // issue V_{c+1} staging (lands during next QK+softmax)
    if (c + 1 < nch) {
#pragma unroll
      for (int it = 0; it < 4; ++it) {
        unsigned p = (unsigned)(it * 4 + wave) * 1024u + (unsigned)lane * 16u;
        unsigned row = p >> 7;
        unsigned gcol = (p & 127u) ^ swz_row(row);
        async_copy16((const char*)(Vb + (size_t)row * 2048 + kc0 + 64) + gcol,
                     Vl + (size_t)(it * 4 + wave) * 1024);
      }
    }
  }

  // epilogue: O rows = q0w + rt*16 + lhi*4 + r, cols f*16 + l16
#pragma unroll
  for (int rt = 0; rt < 2; ++rt)
#pragma unroll
    for (int r = 0; r < 4; ++r) {
      float inv = 1.f / lsum[rt][r];
      int row = q0w + rt * 16 + lhi * 4 + r;
      size_t base = ((size_t)(b * 2048) + row) * 2048 + h * 128;
#pragma unroll
      for (int f = 0; f < 8; ++f)
        attnO[base + f * 16 + l16] = __float2bfloat16(o[rt][f][r] * inv);
    }
}

// ---------------- launch ----------------
extern "C" void kernel_launch(void* const* d_in, const int* in_sizes, int n_in,
                              void* d_out, int out_size, void* d_ws, size_t ws_size,
                              hipStream_t stream) {
  const float* hs = (const float*)d_in[0];
  const float* cosT = (const float*)d_in[2];
  const float* sinT = (const float*)d_in[3];
  const float* Wq = (const float*)d_in[4];
  const float* Wk = (const float*)d_in[5];
  const float* Wv = (const float*)d_in[6];
  const float* Wo = (const float*)d_in[7];
  const float* qw = (const float*)d_in[8];
  const float* kw = (const float*)d_in[9];
  float* out = (float*)d_out;

  char* ws = (char*)d_ws;
  size_t off = 0;
  auto alloc = [&](size_t bytes) {
    char* p = ws + off;
    off += (bytes + 255) & ~(size_t)255;
    return p;
  };
  bf16_t* hsb  = (bf16_t*)alloc((size_t)4096 * 2048 * 2);
  bf16_t* wqkv = (bf16_t*)alloc((size_t)3072 * 2048 * 2);
  bf16_t* wot  = (bf16_t*)alloc((size_t)2048 * 2048 * 2);
  bf16_t* cqkv = (bf16_t*)alloc((size_t)4096 * 3072 * 2);  // QKV gemm out (bf16 now)
  bf16_t* qa   = (bf16_t*)alloc((size_t)2 * 16 * 2048 * 128 * 2);
  bf16_t* ka   = (bf16_t*)alloc((size_t)2 * 4 * 2048 * 128 * 2);
  bf16_t* vt   = (bf16_t*)alloc((size_t)2 * 4 * 2048 * 128 * 2);
  bf16_t* attn = (bf16_t*)cqkv;  // reuse (cqkv dead after relayout kernels)

  convbf_kernel<<<8192, 256, 0, stream>>>(hs, hsb, 2097152);
  dim3 tb(32, 8);
  wtrans_kernel<<<dim3(64, 64), tb, 0, stream>>>(Wq, wqkv, 2048, 0);
  wtrans_kernel<<<dim3(16, 64), tb, 0, stream>>>(Wk, wqkv, 512, 2048);
  wtrans_kernel<<<dim3(16, 64), tb, 0, stream>>>(Wv, wqkv, 512, 2560);
  wtrans_kernel<<<dim3(64, 64), tb, 0, stream>>>(Wo, wot, 2048, 0);
  gemm_bt_kernel<1><<<dim3(24, 32), 256, 0, stream>>>(hsb, wqkv, cqkv, 2048, 3072);
  qknorm_rope_kernel<<<20480, 256, 0, stream>>>(cqkv, cosT, sinT, qw, kw, qa, ka);
  vtrans_kernel<<<dim3(64, 4, 8), tb, 0, stream>>>(cqkv, vt);
  flash_kernel<<<512, 256, 0, stream>>>(qa, ka, vt, attn);
  gemm_bt_kernel<0><<<dim3(16, 32), 256, 0, stream>>>(attn, wot, out, 2048, 2048);
}